// Round 1
// baseline (253.131 us; speedup 1.0000x reference)
//
#include <hip/hip_runtime.h>
#include <hip/hip_bf16.h>
#include <stdint.h>

#define T_STEPS 64
#define B_SZ 8
#define C_DIM 64
#define V_SZ 16000
#define K_DIM 4096   // C*C
#define M_ROWS 512   // T*B
#define BM 128
#define BN 128
#define BK 32

typedef __bf16 bf16x8 __attribute__((ext_vector_type(8)));
typedef float f32x4 __attribute__((ext_vector_type(4)));

__device__ __forceinline__ __bf16 f2bf(float f) { return (__bf16)f; }

__device__ __forceinline__ void gll16(const void* g, void* l) {
  __builtin_amdgcn_global_load_lds(
      (const __attribute__((address_space(1))) void*)g,
      (__attribute__((address_space(3))) void*)l, 16, 0, 0);
}

// ---------------- Kernel 1: sequential ctx recurrence ----------------
// grid = B_SZ blocks, 64 threads (1 wave). Each block owns one batch row.
__global__ void ctx_kernel(const int* __restrict__ tokens,
                           const float* __restrict__ emb_ctx,
                           const float* __restrict__ beta_mult,
                           const float* __restrict__ beta_power,
                           float* __restrict__ ctx_hist) {
  const int b = blockIdx.x;
  const int d = threadIdx.x;
  const float bm = beta_mult[0];
  const float bp = beta_power[0];
  float ctx = 0.0f;
  for (int t = 0; t < T_STEPS; ++t) {
    const int tok = tokens[t * B_SZ + b];
    const float ce = emb_ctx[tok * C_DIM + d];
    float ne2 = ce * ce;
    float c2 = ctx * ctx;
#pragma unroll
    for (int s = 32; s > 0; s >>= 1) {
      ne2 += __shfl_xor(ne2, s, 64);
      c2 += __shfl_xor(c2, s, 64);
    }
    const float ne = sqrtf(ne2);
    const float nc = sqrtf(c2);
    float beta = powf(bm * (ne / (ne + nc)), bp);  // ALPHA == 1
    beta = fminf(fmaxf(beta, 0.0f), 1.0f);
    ctx = (1.0f - beta) * ctx + beta * ce;
    ctx_hist[(t * B_SZ + b) * C_DIM + d] = ctx;
  }
}

// ---------------- Kernel 2: build M[m, c*64+d] = ae[m][c] * ctx[m][d] (bf16) ----
// grid = 512 blocks (m = t*8+b), 128 threads.
__global__ void build_m(const int* __restrict__ tokens,
                        const float* __restrict__ emb_act,
                        const float* __restrict__ ctx_hist,
                        short* __restrict__ Mout) {
  const int m = blockIdx.x;
  const int tid = threadIdx.x;
  __shared__ float ctxs[C_DIM];
  __shared__ float aes[C_DIM];
  const int t = m >> 3, b = m & 7;
  const int tok = tokens[t * B_SZ + b];
  if (tid < C_DIM) {
    ctxs[tid] = ctx_hist[m * C_DIM + tid];
    aes[tid] = emb_act[tok * C_DIM + tid];
  }
  __syncthreads();
  const int c = tid >> 1;
  const int dh = (tid & 1) * 32;
  const float ae = aes[c];
  short* dst = Mout + (size_t)m * K_DIM + c * C_DIM + dh;
#pragma unroll
  for (int q = 0; q < 4; ++q) {
    bf16x8 v;
#pragma unroll
    for (int jj = 0; jj < 8; ++jj) v[jj] = f2bf(ae * ctxs[dh + q * 8 + jj]);
    *(bf16x8*)(void*)(dst + q * 8) = v;
  }
}

// ---------------- Kernel 3: GEMM out[512,16000] = M[512,4096] * W^T ------------
// W is [16000, 4096] f32 row-major (== W_a flat). B^T layout: K contiguous.
// 128x128 tile, BK=32, 4 waves (2x2), 16x16x32 bf16 MFMA, 4x4 frags/wave.
// A staged bf16 via global_load_lds; W staged f32 via global_load_lds,
// converted to bf16 at fragment load. XOR-swizzled LDS (linear dest +
// pre-swizzled global source + swizzled read).
__global__ __launch_bounds__(256, 2)
void gemm_kernel(const short* __restrict__ A, const float* __restrict__ W,
                 float* __restrict__ out) {
  __shared__ short As[BM * BK];  // 8 KB  (swizzled: byte ^= (row&3)<<4)
  __shared__ float Bs[BN * BK];  // 16 KB (swizzled: byte ^= (row&7)<<4)
  char* const Ab = (char*)As;
  char* const Bb = (char*)Bs;

  const int bid = blockIdx.x;
  const int mi = bid & 3;   // M tile (4) — same-W blocks dispatch-adjacent
  const int nj = bid >> 2;  // N tile (125)
  const int m0 = mi * BM;
  const int n0 = nj * BN;

  const int tid = threadIdx.x;
  const int lane = tid & 63;
  const int w = tid >> 6;
  const int wm = w >> 1, wn = w & 1;  // 2x2 wave grid, each wave 64x64
  const int lrow = lane & 15;
  const int g = lane >> 4;  // k-group
  const int k8 = g * 8;

  // staging constants
  const int ar = tid >> 2;             // A: 0..63 rows per issue
  const int ao_phys = (tid & 3) * 16;  // bytes within 64B row
  const int br = tid >> 3;             // B: 0..31 rows per issue
  const int bo_phys = (tid & 7) * 16;  // bytes within 128B row

  const char* const Ac = (const char*)A;
  const char* const Wc = (const char*)W;

  f32x4 acc[4][4];
#pragma unroll
  for (int fm = 0; fm < 4; ++fm)
#pragma unroll
    for (int fn = 0; fn < 4; ++fn) acc[fm][fn] = (f32x4){0.f, 0.f, 0.f, 0.f};

  for (int kt = 0; kt < K_DIM / BK; ++kt) {
    const int kbase = kt * BK;
    // stage A: 128x32 bf16 = 8 KB, 2 issues of 256x16B
#pragma unroll
    for (int s = 0; s < 2; ++s) {
      const int r = s * 64 + ar;
      const int o = ao_phys ^ ((r & 3) << 4);  // pre-swizzle global source
      gll16(Ac + ((size_t)(m0 + r) * K_DIM + kbase) * 2 + o,
            Ab + s * 4096 + tid * 16);
    }
    // stage B(W): 128x32 f32 = 16 KB, 4 issues of 256x16B
#pragma unroll
    for (int s = 0; s < 4; ++s) {
      const int r = s * 32 + br;
      const int o = bo_phys ^ ((r & 7) << 4);
      gll16(Wc + ((size_t)(n0 + r) * K_DIM + kbase) * 4 + o,
            Bb + s * 4096 + tid * 16);
    }
    __syncthreads();  // vmcnt(0) drain + barrier: LDS tiles ready

    bf16x8 a[4];
#pragma unroll
    for (int fm = 0; fm < 4; ++fm) {
      const int row = wm * 64 + fm * 16 + lrow;
      a[fm] = *(const bf16x8*)(Ab + row * 64 + ((k8 * 2) ^ ((row & 3) << 4)));
    }
#pragma unroll
    for (int fn = 0; fn < 4; ++fn) {
      const int col = wn * 64 + fn * 16 + lrow;
      const int x = (col & 7) << 4;
      const f32x4 b0 = *(const f32x4*)(Bb + col * 128 + ((k8 * 4) ^ x));
      const f32x4 b1 = *(const f32x4*)(Bb + col * 128 + ((k8 * 4 + 16) ^ x));
      bf16x8 bv;
      bv[0] = f2bf(b0[0]); bv[1] = f2bf(b0[1]);
      bv[2] = f2bf(b0[2]); bv[3] = f2bf(b0[3]);
      bv[4] = f2bf(b1[0]); bv[5] = f2bf(b1[1]);
      bv[6] = f2bf(b1[2]); bv[7] = f2bf(b1[3]);
#pragma unroll
      for (int fm = 0; fm < 4; ++fm)
        acc[fm][fn] =
            __builtin_amdgcn_mfma_f32_16x16x32_bf16(a[fm], bv, acc[fm][fn], 0, 0, 0);
    }
    __syncthreads();  // all reads done before next stage overwrites
  }

  // epilogue: C/D layout col=lane&15, row=(lane>>4)*4+reg
  const int orow0 = m0 + wm * 64;
  const int ocol0 = n0 + wn * 64 + lrow;
  const int rg = g * 4;
#pragma unroll
  for (int fm = 0; fm < 4; ++fm)
#pragma unroll
    for (int fn = 0; fn < 4; ++fn)
#pragma unroll
      for (int q = 0; q < 4; ++q)
        out[(size_t)(orow0 + fm * 16 + rg + q) * V_SZ + ocol0 + fn * 16] =
            acc[fm][fn][q];
}

extern "C" void kernel_launch(void* const* d_in, const int* in_sizes, int n_in,
                              void* d_out, int out_size, void* d_ws, size_t ws_size,
                              hipStream_t stream) {
  const int* tokens = (const int*)d_in[0];
  const float* emb_ctx = (const float*)d_in[1];
  const float* emb_act = (const float*)d_in[2];
  const float* W = (const float*)d_in[3];
  const float* beta_mult = (const float*)d_in[4];
  const float* beta_power = (const float*)d_in[5];
  float* out = (float*)d_out;

  short* Mbuf = (short*)d_ws;  // 512*4096*2 = 4 MB
  float* ctx_hist = (float*)((char*)d_ws + (size_t)M_ROWS * K_DIM * 2);  // 128 KB

  ctx_kernel<<<B_SZ, C_DIM, 0, stream>>>(tokens, emb_ctx, beta_mult, beta_power,
                                         ctx_hist);
  build_m<<<M_ROWS, 128, 0, stream>>>(tokens, emb_act, ctx_hist, Mbuf);
  gemm_kernel<<<(M_ROWS / BM) * (V_SZ / BN), 256, 0, stream>>>(Mbuf, W, out);
}